// Round 7
// baseline (464.992 us; speedup 1.0000x reference)
//
#include <hip/hip_runtime.h>
#include <math.h>
#include <stdint.h>

// ---------------------------------------------------------------------------
// KAN forward, split-bf16 MFMA, round 7.
//   Round-6 dataflow (Wh LDS-dbuf + Wl->regs via L2, one barrier/chunk) at
//   DOUBLE block residency: 32-row blocks, grid 1024 -> 4 blocks/CU,
//   16 waves/CU. Wave = 16 rows x 128 cols, 1 A-build per wave per chunk.
//   3-product split emulation: Ah*Wh + Al*Wh + Ah*Wl  (error ~2^-16 rel).
// ---------------------------------------------------------------------------

#define N_PTS 32768

using short8 = __attribute__((ext_vector_type(8))) short;
using f32x4  = __attribute__((ext_vector_type(4))) float;

union Frag { short8 v; uint32_t u[4]; };

__device__ __forceinline__ uint32_t bf16rne(float f) {
    uint32_t u = __float_as_uint(f);
    return (u + 0x7FFFu + ((u >> 16) & 1u)) >> 16;
}
__device__ __forceinline__ float bf16tof(uint32_t h) { return __uint_as_float(h << 16); }

// pack bf16-trunc(x0) lo16, bf16-trunc(x1) hi16 — one v_perm_b32
__device__ __forceinline__ uint32_t pkhi(uint32_t x0, uint32_t x1) {
    return __builtin_amdgcn_perm(x1, x0, 0x07060302u);
}

// async global->LDS, 16B per lane
__device__ __forceinline__ void gld16(const void* g, void* lds) {
    __builtin_amdgcn_global_load_lds(
        (const __attribute__((address_space(1))) void*)(uintptr_t)g,
        (__attribute__((address_space(3))) void*)(uint32_t)(uintptr_t)lds,
        16, 0, 0);
}

// ---------------------------------------------------------------------------
// cardinal cubic B-spline pieces: t=(x+2.2)*2.5, i=floor(t), w=frac
__device__ __forceinline__ void spline_q(float x, int& i, float& q0, float& q1,
                                         float& q2, float& q3) {
    float t  = (x + 2.2f) * 2.5f;
    float fl = floorf(t);
    i = (int)fl;
    float w  = t - fl;
    float w2 = w * w, w3 = w2 * w;
    const float s = 1.0f / 6.0f;
    q0 = w3 * s;
    q1 = (-3.f * w3 + 3.f * w2 + 3.f * w + 1.f) * s;
    q2 = (3.f * w3 - 6.f * w2 + 4.f) * s;
    float omw = 1.f - w;
    q3 = omw * omw * omw * s;
}

__device__ __forceinline__ void build_basis_frag(float x, Frag& ah, Frag& al) {
    int i; float q0, q1, q2, q3;
    spline_q(x, i, q0, q1, q2, q3);
    uint32_t u0 = __float_as_uint(q0), u1 = __float_as_uint(q1);
    uint32_t u2 = __float_as_uint(q2), u3 = __float_as_uint(q3);
    uint32_t r0 = __float_as_uint(q0 - __uint_as_float(u0 & 0xFFFF0000u));
    uint32_t r1 = __float_as_uint(q1 - __uint_as_float(u1 & 0xFFFF0000u));
    uint32_t r2 = __float_as_uint(q2 - __uint_as_float(u2 & 0xFFFF0000u));
    uint32_t r3 = __float_as_uint(q3 - __uint_as_float(u3 & 0xFFFF0000u));
    uint32_t PH0 = pkhi(u0, 0u), PH1 = pkhi(u1, u0), PH2 = pkhi(u2, u1),
             PH3 = pkhi(u3, u2), PH4 = pkhi(0u, u3);
    uint32_t PL0 = pkhi(r0, 0u), PL1 = pkhi(r1, r0), PL2 = pkhi(r2, r1),
             PL3 = pkhi(r3, r2), PL4 = pkhi(0u, r3);
#pragma unroll
    for (int p = 0; p < 4; ++p) {
        bool c0 = (i == 2 * p), c1 = (i == 2 * p + 1), c2 = (i == 2 * p + 2),
             c3 = (i == 2 * p + 3), c4 = (i == 2 * p + 4);
        ah.u[p] = c0 ? PH0 : c1 ? PH1 : c2 ? PH2 : c3 ? PH3 : c4 ? PH4 : 0u;
        al.u[p] = c0 ? PL0 : c1 ? PL1 : c2 ? PL2 : c3 ? PL3 : c4 ? PL4 : 0u;
    }
}

__device__ __forceinline__ void build_silu_frag(const float* __restrict__ xp, Frag& ah, Frag& al) {
    float4 a = *(const float4*)xp;
    float4 b = *(const float4*)(xp + 4);
    float xs[8] = {a.x, a.y, a.z, a.w, b.x, b.y, b.z, b.w};
#pragma unroll
    for (int p = 0; p < 4; ++p) {
        float x0 = xs[p * 2], x1 = xs[p * 2 + 1];
        float v0 = x0 / (1.f + __expf(-x0));
        float v1 = x1 / (1.f + __expf(-x1));
        uint32_t w0 = __float_as_uint(v0), w1 = __float_as_uint(v1);
        uint32_t l0 = __float_as_uint(v0 - __uint_as_float(w0 & 0xFFFF0000u));
        uint32_t l1 = __float_as_uint(v1 - __uint_as_float(w1 & 0xFFFF0000u));
        ah.u[p] = pkhi(w0, w1);
        al.u[p] = pkhi(l0, l1);
    }
}

// ---------------------------------------------------------------------------
__global__ void encode_kernel(const float* __restrict__ x,
                              const float* __restrict__ freq,
                              float* __restrict__ h0) {
    int n = blockIdx.x * blockDim.x + threadIdx.x;
    if (n >= N_PTS) return;
    float xv = x[n];
#pragma unroll
    for (int l = 0; l < 16; ++l) {
        float e = xv * freq[l];
        h0[n * 32 + l]      = sinf(e);
        h0[n * 32 + 16 + l] = cosf(e);
    }
}

// Fold sw*ss (k=f*8+j) and bw (k=8F+f) into split-bf16 pair,
// layout Wh/Wl[(k>>3)][col][k&7] (flat-contiguous 16 KB per 32-k chunk).
__global__ void prep_kernel(const float* __restrict__ bw,
                            const float* __restrict__ sw,
                            const float* __restrict__ ss,
                            short* __restrict__ Wh, short* __restrict__ Wl, int F) {
    int id = blockIdx.x * blockDim.x + threadIdx.x;
    int K = 9 * F;
    if (id >= K * 256) return;
    int col = id & 255;
    int k   = id >> 8;
    float wv;
    if (k < 8 * F) {
        int f = k >> 3, j = k & 7;
        wv = sw[(col * F + f) * 8 + j] * ss[col * F + f];
    } else {
        int f = k - 8 * F;
        wv = bw[col * F + f];
    }
    uint32_t hh = bf16rne(wv);
    uint32_t ll = bf16rne(wv - bf16tof(hh));
    size_t idx = ((size_t)(k >> 3) * 256 + col) * 8 + (k & 7);
    Wh[idx] = (short)hh;
    Wl[idx] = (short)ll;
}

// padded layer3 table: wp[f][m] = sw3[f][m-4]*ss3[f] for m in [4,12) else 0
__global__ void prep3_kernel(const float* __restrict__ sw3,
                             const float* __restrict__ ss3,
                             float* __restrict__ wp) {
    int id = blockIdx.x * blockDim.x + threadIdx.x;   // 256*20
    if (id >= 256 * 20) return;
    int f = id / 20, m = id % 20;
    float v = 0.f;
    if (m >= 4 && m < 12) v = sw3[f * 8 + (m - 4)] * ss3[f];
    wp[id] = v;
}

// ---------------------------------------------------------------------------
// out(N,256) = Aug(h)(N,9F) @ W(9F,256), split-bf16 MFMA.
// Grid N/32: block = 32 rows x 256 cols, 256 threads = 4 waves;
// wave = 16 rows x 128 cols (8 ct). Wh dbuf LDS; Wl global->regs;
// one barrier per chunk; 4 blocks/CU.
template <int F>
__global__ __launch_bounds__(256, 4)
void layer_mfma(const float* __restrict__ hin,
                const short* __restrict__ Wh, const short* __restrict__ Wl,
                float* __restrict__ out) {
    constexpr int KBC = F / 4;    // basis chunks
    constexpr int NC  = KBC + F / 32;
    __shared__ short WB[2][8192];   // Wh chunk dbuf, 2x16 KB

    const int tid  = threadIdx.x;
    const int w    = tid >> 6;
    const int wy   = w >> 1, wx = w & 1;
    const int lane = tid & 63;
    const int lr   = lane & 15, quad = lane >> 4;
    const int row0 = blockIdx.x * 32 + wy * 16;
    const int fragoff = (quad * 256 + wx * 128 + lr) * 8;   // + ct*128

    f32x4 acc[8];
#pragma unroll
    for (int a2 = 0; a2 < 8; ++a2) acc[a2] = (f32x4){0.f, 0.f, 0.f, 0.f};

    Frag A0, L0, A1, L1;   // parity A-frag sets (ah, al)
    Frag WlF[8];           // Wl fragments for the CURRENT chunk

    // ---- preamble: stage chunk 0, build frags(0) ----
#pragma unroll
    for (int i = 0; i < 4; ++i) {
        int e = tid * 8 + i * 2048;
        gld16(Wh + e, &WB[0][e]);
    }
    {
        float x0 = hin[(size_t)(row0 + lr) * F + quad];
        build_basis_frag(x0, A0, L0);
    }
    __syncthreads();   // stage(0) visible

    // ---- one step: MFMA(c) with cur A-set; prep c+1 into nxt set ----
    auto step = [&](int c, Frag& Ac, Frag& Lc, Frag& An, Frag& Ln) {
        const int cn = c + 1;
        const size_t gofc = (size_t)c * 8192;
        // 1) Wl(c) fragments -> regs (needed at product 3, ~600 cyc away)
#pragma unroll
        for (int ct = 0; ct < 8; ++ct)
            WlF[ct].v = *(const short8*)(Wl + gofc + fragoff + ct * 128);
        // 2) stage Wh(c+1) into other LDS buffer
        if (cn < NC) {
            const size_t gof = (size_t)cn * 8192;
#pragma unroll
            for (int i = 0; i < 4; ++i) {
                int e = tid * 8 + i * 2048;
                gld16(Wh + gof + e, &WB[cn & 1][e]);
            }
        }
        // 3) x prefetch for basis build(c+1)
        float xn = 0.f;
        if (cn < KBC)
            xn = hin[(size_t)(row0 + lr) * F + cn * 4 + quad];
        // 4) products 1&2: Wh from LDS buf[c&1]
#pragma unroll
        for (int ct = 0; ct < 8; ++ct) {
            Frag wh;
            wh.v = *(const short8*)&WB[c & 1][fragoff + ct * 128];
            acc[ct] = __builtin_amdgcn_mfma_f32_16x16x32_bf16(Ac.v, wh.v, acc[ct], 0, 0, 0);
            acc[ct] = __builtin_amdgcn_mfma_f32_16x16x32_bf16(Lc.v, wh.v, acc[ct], 0, 0, 0);
        }
        // 5) build frags(c+1) — interleaves with MFMA issue
        if (cn < NC) {
            if (cn < KBC) {
                build_basis_frag(xn, An, Ln);
            } else {
                const int fb = (cn - KBC) * 32 + quad * 8;
                build_silu_frag(&hin[(size_t)(row0 + lr) * F + fb], An, Ln);
            }
        }
        // 6) product 3: Wl from regs
#pragma unroll
        for (int ct = 0; ct < 8; ++ct)
            acc[ct] = __builtin_amdgcn_mfma_f32_16x16x32_bf16(Ac.v, WlF[ct].v, acc[ct], 0, 0, 0);
        // 7) single barrier per chunk: stage(c+1) has had a full MFMA phase
        //    in flight; also closes WAR for the c+2 overwrite of buf[c&1].
        __syncthreads();
    };

    for (int c = 0; c < NC; c += 2) {
        step(c, A0, L0, A1, L1);
        if (c + 1 < NC) step(c + 1, A1, L1, A0, L0);
    }

    // ---- epilogue: C/D col=lane&15, row=quad*4+reg ----
    const int rbase = row0 + quad * 4;
#pragma unroll
    for (int ct = 0; ct < 8; ++ct) {
        const int colg = wx * 128 + ct * 16 + lr;
#pragma unroll
        for (int rg = 0; rg < 4; ++rg)
            out[(size_t)(rbase + rg) * 256 + colg] = acc[ct][rg];
    }
}

// ---------------------------------------------------------------------------
// Final layer (n_out=1): one wave per row; cardinal spline + padded table.
__global__ void layer3_kernel(const float* __restrict__ hin,
                              const float* __restrict__ wp,
                              const float* __restrict__ bw,
                              float* __restrict__ out) {
    int gid  = blockIdx.x * blockDim.x + threadIdx.x;
    int row  = gid >> 6;
    int lane = gid & 63;
    if (row >= N_PTS) return;
    float acc = 0.0f;
#pragma unroll
    for (int it = 0; it < 4; ++it) {
        int f = lane + it * 64;
        float x = hin[(size_t)row * 256 + f];
        int i; float q0, q1, q2, q3;
        spline_q(x, i, q0, q1, q2, q3);
        i = min(max(i, -1), 15);
        const float* wrow = wp + f * 20;
        float dot = q0 * wrow[i + 4] + q1 * wrow[i + 3]
                  + q2 * wrow[i + 2] + q3 * wrow[i + 1];
        acc += dot;
        acc = fmaf(x / (1.0f + __expf(-x)), bw[f], acc);
    }
#pragma unroll
    for (int off = 32; off > 0; off >>= 1) acc += __shfl_down(acc, off);
    if (lane == 0) out[row] = acc;
}

// ---------------------------------------------------------------------------
// ws layout (bytes)
#define WH0_OFF 0u
#define WL0_OFF (WH0_OFF + 147456u)      // 288*256*2
#define WH1_OFF (WL0_OFF + 147456u)
#define WL1_OFF (WH1_OFF + 1179648u)     // 2304*256*2
#define WH2_OFF (WL1_OFF + 1179648u)
#define WL2_OFF (WH2_OFF + 1179648u)
#define H0_OFF  (WL2_OFF + 1179648u)     // 32768*32*4
#define HA_OFF  (H0_OFF + 4194304u)      // 32768*256*4
#define HB_OFF  (HA_OFF + 33554432u)
// WP3 reuses the (dead after layer0) h0 region; prep3 runs after layer0.
#define WP3_OFF H0_OFF

extern "C" void kernel_launch(void* const* d_in, const int* in_sizes, int n_in,
                              void* d_out, int out_size, void* d_ws, size_t ws_size,
                              hipStream_t stream) {
    const float* x    = (const float*)d_in[0];
    const float* freq = (const float*)d_in[1];
    const float* bw0  = (const float*)d_in[2];
    const float* sw0  = (const float*)d_in[3];
    const float* ss0  = (const float*)d_in[4];
    const float* bw1  = (const float*)d_in[5];
    const float* sw1  = (const float*)d_in[6];
    const float* ss1  = (const float*)d_in[7];
    const float* bw2  = (const float*)d_in[8];
    const float* sw2  = (const float*)d_in[9];
    const float* ss2  = (const float*)d_in[10];
    const float* bw3  = (const float*)d_in[11];
    const float* sw3  = (const float*)d_in[12];
    const float* ss3  = (const float*)d_in[13];

    char* ws = (char*)d_ws;
    short* Wh0 = (short*)(ws + WH0_OFF);
    short* Wl0 = (short*)(ws + WL0_OFF);
    short* Wh1 = (short*)(ws + WH1_OFF);
    short* Wl1 = (short*)(ws + WL1_OFF);
    short* Wh2 = (short*)(ws + WH2_OFF);
    short* Wl2 = (short*)(ws + WL2_OFF);
    float* h0  = (float*)(ws + H0_OFF);
    float* wp3 = (float*)(ws + WP3_OFF);
    float* hA  = (float*)(ws + HA_OFF);
    float* hB  = (float*)(ws + HB_OFF);
    float* outp = (float*)d_out;

    prep_kernel<<<288, 256, 0, stream>>>(bw0, sw0, ss0, Wh0, Wl0, 32);
    prep_kernel<<<2304, 256, 0, stream>>>(bw1, sw1, ss1, Wh1, Wl1, 256);
    prep_kernel<<<2304, 256, 0, stream>>>(bw2, sw2, ss2, Wh2, Wl2, 256);

    encode_kernel<<<(N_PTS + 255) / 256, 256, 0, stream>>>(x, freq, h0);

    layer_mfma<32><<<N_PTS / 32, 256, 0, stream>>>(h0, Wh0, Wl0, hA);
    prep3_kernel<<<(256 * 20 + 255) / 256, 256, 0, stream>>>(sw3, ss3, wp3); // h0 dead now
    layer_mfma<256><<<N_PTS / 32, 256, 0, stream>>>(hA, Wh1, Wl1, hB);
    layer_mfma<256><<<N_PTS / 32, 256, 0, stream>>>(hB, Wh2, Wl2, hA);

    layer3_kernel<<<(N_PTS * 64) / 256, 256, 0, stream>>>(hA, wp3, bw3, outp);
}

// Round 8
// 407.042 us; speedup vs baseline: 1.1424x; 1.1424x over previous
//
#include <hip/hip_runtime.h>
#include <math.h>
#include <stdint.h>

// ---------------------------------------------------------------------------
// KAN forward, split-bf16 MFMA, round 8.
//   R3 dataflow (Wh+Wl both via global_load_lds -> 64 KB LDS dbuf, 64-row
//   blocks, wave = 32r x 128c) with ONE barrier per chunk placed AFTER the
//   MFMA phase, so the vmcnt(0) drain of stage(c+1) is covered by compute.
//   (R3 drained its own just-issued prefetch at barrier #1 — the big stall.)
//   Fused prep+encode single launch; layer3 reads sw3/ss3 directly.
//   3-product split emulation: Ah*Wh + Al*Wh + Ah*Wl  (error ~2^-16 rel).
// ---------------------------------------------------------------------------

#define N_PTS 32768

using short8 = __attribute__((ext_vector_type(8))) short;
using f32x4  = __attribute__((ext_vector_type(4))) float;

union Frag { short8 v; uint32_t u[4]; };

__device__ __forceinline__ uint32_t bf16rne(float f) {
    uint32_t u = __float_as_uint(f);
    return (u + 0x7FFFu + ((u >> 16) & 1u)) >> 16;
}
__device__ __forceinline__ float bf16tof(uint32_t h) { return __uint_as_float(h << 16); }

// pack bf16-trunc(x0) lo16, bf16-trunc(x1) hi16 — one v_perm_b32
__device__ __forceinline__ uint32_t pkhi(uint32_t x0, uint32_t x1) {
    return __builtin_amdgcn_perm(x1, x0, 0x07060302u);
}

// async global->LDS, 16B per lane
__device__ __forceinline__ void gld16(const void* g, void* lds) {
    __builtin_amdgcn_global_load_lds(
        (const __attribute__((address_space(1))) void*)(uintptr_t)g,
        (__attribute__((address_space(3))) void*)(uint32_t)(uintptr_t)lds,
        16, 0, 0);
}

// ---------------------------------------------------------------------------
// cardinal cubic B-spline pieces: t=(x+2.2)*2.5, i=floor(t), w=frac
__device__ __forceinline__ void spline_q(float x, int& i, float& q0, float& q1,
                                         float& q2, float& q3) {
    float t  = (x + 2.2f) * 2.5f;
    float fl = floorf(t);
    i = (int)fl;
    float w  = t - fl;
    float w2 = w * w, w3 = w2 * w;
    const float s = 1.0f / 6.0f;
    q0 = w3 * s;
    q1 = (-3.f * w3 + 3.f * w2 + 3.f * w + 1.f) * s;
    q2 = (3.f * w3 - 6.f * w2 + 4.f) * s;
    float omw = 1.f - w;
    q3 = omw * omw * omw * s;
}

__device__ __forceinline__ void build_basis_frag(float x, Frag& ah, Frag& al) {
    int i; float q0, q1, q2, q3;
    spline_q(x, i, q0, q1, q2, q3);
    uint32_t u0 = __float_as_uint(q0), u1 = __float_as_uint(q1);
    uint32_t u2 = __float_as_uint(q2), u3 = __float_as_uint(q3);
    uint32_t r0 = __float_as_uint(q0 - __uint_as_float(u0 & 0xFFFF0000u));
    uint32_t r1 = __float_as_uint(q1 - __uint_as_float(u1 & 0xFFFF0000u));
    uint32_t r2 = __float_as_uint(q2 - __uint_as_float(u2 & 0xFFFF0000u));
    uint32_t r3 = __float_as_uint(q3 - __uint_as_float(u3 & 0xFFFF0000u));
    uint32_t PH0 = pkhi(u0, 0u), PH1 = pkhi(u1, u0), PH2 = pkhi(u2, u1),
             PH3 = pkhi(u3, u2), PH4 = pkhi(0u, u3);
    uint32_t PL0 = pkhi(r0, 0u), PL1 = pkhi(r1, r0), PL2 = pkhi(r2, r1),
             PL3 = pkhi(r3, r2), PL4 = pkhi(0u, r3);
#pragma unroll
    for (int p = 0; p < 4; ++p) {
        bool c0 = (i == 2 * p), c1 = (i == 2 * p + 1), c2 = (i == 2 * p + 2),
             c3 = (i == 2 * p + 3), c4 = (i == 2 * p + 4);
        ah.u[p] = c0 ? PH0 : c1 ? PH1 : c2 ? PH2 : c3 ? PH3 : c4 ? PH4 : 0u;
        al.u[p] = c0 ? PL0 : c1 ? PL1 : c2 ? PL2 : c3 ? PL3 : c4 ? PL4 : 0u;
    }
}

__device__ __forceinline__ void build_silu_frag(const float* __restrict__ xp, Frag& ah, Frag& al) {
    float4 a = *(const float4*)xp;
    float4 b = *(const float4*)(xp + 4);
    float xs[8] = {a.x, a.y, a.z, a.w, b.x, b.y, b.z, b.w};
#pragma unroll
    for (int p = 0; p < 4; ++p) {
        float x0 = xs[p * 2], x1 = xs[p * 2 + 1];
        float v0 = x0 / (1.f + __expf(-x0));
        float v1 = x1 / (1.f + __expf(-x1));
        uint32_t w0 = __float_as_uint(v0), w1 = __float_as_uint(v1);
        uint32_t l0 = __float_as_uint(v0 - __uint_as_float(w0 & 0xFFFF0000u));
        uint32_t l1 = __float_as_uint(v1 - __uint_as_float(w1 & 0xFFFF0000u));
        ah.u[p] = pkhi(w0, w1);
        al.u[p] = pkhi(l0, l1);
    }
}

// ---------------------------------------------------------------------------
// Fold sw*ss (k=f*8+j) and bw (k=8F+f) into split-bf16 pair,
// layout Wh/Wl[(k>>3)][col][k&7] (flat-contiguous 16 KB per 32-k chunk).
__device__ __forceinline__ void prep_body(const float* __restrict__ bw,
                                          const float* __restrict__ sw,
                                          const float* __restrict__ ss,
                                          short* __restrict__ Wh,
                                          short* __restrict__ Wl,
                                          int F, int id) {
    int col = id & 255;
    int k   = id >> 8;
    float wv;
    if (k < 8 * F) {
        int f = k >> 3, j = k & 7;
        wv = sw[(col * F + f) * 8 + j] * ss[col * F + f];
    } else {
        int f = k - 8 * F;
        wv = bw[col * F + f];
    }
    uint32_t hh = bf16rne(wv);
    uint32_t ll = bf16rne(wv - bf16tof(hh));
    size_t idx = ((size_t)(k >> 3) * 256 + col) * 8 + (k & 7);
    Wh[idx] = (short)hh;
    Wl[idx] = (short)ll;
}

// Fused prep of all three layers' W + the sin/cos encoding — one launch.
// Block ranges: [0,288) L0, [288,2592) L1, [2592,4896) L2, [4896,5024) encode.
__global__ void fused_prep(const float* __restrict__ x,
                           const float* __restrict__ freq,
                           const float* __restrict__ bw0, const float* __restrict__ sw0, const float* __restrict__ ss0,
                           const float* __restrict__ bw1, const float* __restrict__ sw1, const float* __restrict__ ss1,
                           const float* __restrict__ bw2, const float* __restrict__ sw2, const float* __restrict__ ss2,
                           short* __restrict__ Wh0, short* __restrict__ Wl0,
                           short* __restrict__ Wh1, short* __restrict__ Wl1,
                           short* __restrict__ Wh2, short* __restrict__ Wl2,
                           float* __restrict__ h0) {
    int b = blockIdx.x;
    int t = threadIdx.x;
    if (b < 288) {
        prep_body(bw0, sw0, ss0, Wh0, Wl0, 32, b * 256 + t);
    } else if (b < 2592) {
        prep_body(bw1, sw1, ss1, Wh1, Wl1, 256, (b - 288) * 256 + t);
    } else if (b < 4896) {
        prep_body(bw2, sw2, ss2, Wh2, Wl2, 256, (b - 2592) * 256 + t);
    } else {
        int n = (b - 4896) * 256 + t;
        float xv = x[n];
#pragma unroll
        for (int l = 0; l < 16; ++l) {
            float e = xv * freq[l];
            h0[n * 32 + l]      = sinf(e);
            h0[n * 32 + 16 + l] = cosf(e);
        }
    }
}

// ---------------------------------------------------------------------------
// out(N,256) = Aug(h)(N,9F) @ W(9F,256), split-bf16 MFMA.
// Block: 64 rows x 256 cols, 256 threads = 4 waves; wave = 32r x 128c
// (2 rt x 8 ct). Wh+Wl dbuf in LDS via gld16 (2x32 KB); ONE barrier per
// chunk, placed after MFMA(c)+builds(c+1) so the stage(c+1) drain is covered.
template <int F>
__global__ __launch_bounds__(256, 2)
void layer_mfma(const float* __restrict__ hin,
                const short* __restrict__ Wh, const short* __restrict__ Wl,
                float* __restrict__ out) {
    constexpr int KBC = F / 4;    // basis chunks
    constexpr int NC  = KBC + F / 32;
    __shared__ short WB[2][2][8192];   // [buf][h/l][32k x 256col] = 64 KB

    const int tid  = threadIdx.x;
    const int w    = tid >> 6;
    const int wy   = w >> 1, wx = w & 1;
    const int lane = tid & 63;
    const int lr   = lane & 15, quad = lane >> 4;
    const int row0 = blockIdx.x * 64 + wy * 32;
    const int fragoff = (quad * 256 + wx * 128 + lr) * 8;   // + ct*128

    f32x4 acc[2][8];
#pragma unroll
    for (int a1 = 0; a1 < 2; ++a1)
#pragma unroll
        for (int a2 = 0; a2 < 8; ++a2) acc[a1][a2] = (f32x4){0.f, 0.f, 0.f, 0.f};

    Frag A0[2], L0[2], A1[2], L1[2];   // parity A-frag sets (ah, al)

    // ---- preamble: stage chunk 0 into buf0, build frags(0) ----
#pragma unroll
    for (int i = 0; i < 4; ++i) {
        int e = tid * 8 + i * 2048;
        gld16(Wh + e, &WB[0][0][e]);
        gld16(Wl + e, &WB[0][1][e]);
    }
#pragma unroll
    for (int rt = 0; rt < 2; ++rt) {
        float x0 = hin[(size_t)(row0 + rt * 16 + lr) * F + quad];
        build_basis_frag(x0, A0[rt], L0[rt]);
    }
    __syncthreads();   // stage(0) drained & visible

    // ---- one step: stage(c+1); MFMA(c); build(c+1); barrier ----
    auto step = [&](int c, Frag (&Ac)[2], Frag (&Lc)[2],
                    Frag (&An)[2], Frag (&Ln)[2]) {
        const int cn = c + 1;
        // 1) issue stage(c+1) into the other buffer (fire-and-forget;
        //    WAR safe: reads of that buffer ended at the previous barrier)
        if (cn < NC) {
            const size_t gof = (size_t)cn * 8192;
#pragma unroll
            for (int i = 0; i < 4; ++i) {
                int e = tid * 8 + i * 2048;
                gld16(Wh + gof + e, &WB[cn & 1][0][e]);
                gld16(Wl + gof + e, &WB[cn & 1][1][e]);
            }
        }
        // 2) x prefetch for basis build(c+1)
        float xn[2];
        if (cn < KBC) {
#pragma unroll
            for (int rt = 0; rt < 2; ++rt)
                xn[rt] = hin[(size_t)(row0 + rt * 16 + lr) * F + cn * 4 + quad];
        }
        // 3) MFMA(c): both W streams from LDS buf[c&1]
#pragma unroll
        for (int ct = 0; ct < 8; ++ct) {
            Frag wh, wl;
            wh.v = *(const short8*)&WB[c & 1][0][fragoff + ct * 128];
            wl.v = *(const short8*)&WB[c & 1][1][fragoff + ct * 128];
#pragma unroll
            for (int rt = 0; rt < 2; ++rt) {
                acc[rt][ct] = __builtin_amdgcn_mfma_f32_16x16x32_bf16(Ac[rt].v, wh.v, acc[rt][ct], 0, 0, 0);
                acc[rt][ct] = __builtin_amdgcn_mfma_f32_16x16x32_bf16(Lc[rt].v, wh.v, acc[rt][ct], 0, 0, 0);
                acc[rt][ct] = __builtin_amdgcn_mfma_f32_16x16x32_bf16(Ac[rt].v, wl.v, acc[rt][ct], 0, 0, 0);
            }
        }
        // 4) build frags(c+1) — interleaves with MFMA issue
        if (cn < NC) {
            if (cn < KBC) {
#pragma unroll
                for (int rt = 0; rt < 2; ++rt)
                    build_basis_frag(xn[rt], An[rt], Ln[rt]);
            } else {
                const int fb = (cn - KBC) * 32 + quad * 8;
#pragma unroll
                for (int rt = 0; rt < 2; ++rt)
                    build_silu_frag(&hin[(size_t)(row0 + rt * 16 + lr) * F + fb], An[rt], Ln[rt]);
            }
        }
        // 5) ONE barrier: stage(c+1) has had the whole MFMA phase in flight,
        //    so the vmcnt(0) drain here is nearly free; also closes the WAR
        //    window for the c+2 overwrite of buf[c&1].
        __syncthreads();
    };

    for (int c = 0; c < NC; c += 2) {
        step(c, A0, L0, A1, L1);
        if (c + 1 < NC) step(c + 1, A1, L1, A0, L0);
    }

    // ---- epilogue: C/D col=lane&15, row=quad*4+reg ----
#pragma unroll
    for (int rt = 0; rt < 2; ++rt) {
        const int rbase = row0 + rt * 16 + quad * 4;
#pragma unroll
        for (int ct = 0; ct < 8; ++ct) {
            const int colg = wx * 128 + ct * 16 + lr;
#pragma unroll
            for (int rg = 0; rg < 4; ++rg)
                out[(size_t)(rbase + rg) * 256 + colg] = acc[rt][ct][rg];
        }
    }
}

// ---------------------------------------------------------------------------
// Final layer (n_out=1): one wave per row; cardinal spline, direct sw3/ss3
// reads (8 KB tables, L1/L2-resident), window-masked — no prep table needed.
__global__ void layer3_kernel(const float* __restrict__ hin,
                              const float* __restrict__ sw3,
                              const float* __restrict__ ss3,
                              const float* __restrict__ bw,
                              float* __restrict__ out) {
    int gid  = blockIdx.x * blockDim.x + threadIdx.x;
    int row  = gid >> 6;
    int lane = gid & 63;
    if (row >= N_PTS) return;
    float acc = 0.0f;
#pragma unroll
    for (int it = 0; it < 4; ++it) {
        int f = lane + it * 64;
        float x = hin[(size_t)row * 256 + f];
        int i; float q[4];
        spline_q(x, i, q[0], q[1], q[2], q[3]);
        float dot = 0.0f;
#pragma unroll
        for (int d = 0; d < 4; ++d) {
            int j = i - d;
            float wv = ((unsigned)j < 8u) ? sw3[f * 8 + (j & 7)] : 0.0f;
            dot = fmaf(q[d], wv, dot);
        }
        acc = fmaf(dot, ss3[f], acc);
        acc = fmaf(x / (1.0f + __expf(-x)), bw[f], acc);
    }
#pragma unroll
    for (int off = 32; off > 0; off >>= 1) acc += __shfl_down(acc, off);
    if (lane == 0) out[row] = acc;
}

// ---------------------------------------------------------------------------
// ws layout (bytes)
#define WH0_OFF 0u
#define WL0_OFF (WH0_OFF + 147456u)      // 288*256*2
#define WH1_OFF (WL0_OFF + 147456u)
#define WL1_OFF (WH1_OFF + 1179648u)     // 2304*256*2
#define WH2_OFF (WL1_OFF + 1179648u)
#define WL2_OFF (WH2_OFF + 1179648u)
#define H0_OFF  (WL2_OFF + 1179648u)     // 32768*32*4
#define HA_OFF  (H0_OFF + 4194304u)      // 32768*256*4
#define HB_OFF  (HA_OFF + 33554432u)
// total = 76,316,672 B

extern "C" void kernel_launch(void* const* d_in, const int* in_sizes, int n_in,
                              void* d_out, int out_size, void* d_ws, size_t ws_size,
                              hipStream_t stream) {
    const float* x    = (const float*)d_in[0];
    const float* freq = (const float*)d_in[1];
    const float* bw0  = (const float*)d_in[2];
    const float* sw0  = (const float*)d_in[3];
    const float* ss0  = (const float*)d_in[4];
    const float* bw1  = (const float*)d_in[5];
    const float* sw1  = (const float*)d_in[6];
    const float* ss1  = (const float*)d_in[7];
    const float* bw2  = (const float*)d_in[8];
    const float* sw2  = (const float*)d_in[9];
    const float* ss2  = (const float*)d_in[10];
    const float* bw3  = (const float*)d_in[11];
    const float* sw3  = (const float*)d_in[12];
    const float* ss3  = (const float*)d_in[13];

    char* ws = (char*)d_ws;
    short* Wh0 = (short*)(ws + WH0_OFF);
    short* Wl0 = (short*)(ws + WL0_OFF);
    short* Wh1 = (short*)(ws + WH1_OFF);
    short* Wl1 = (short*)(ws + WL1_OFF);
    short* Wh2 = (short*)(ws + WH2_OFF);
    short* Wl2 = (short*)(ws + WL2_OFF);
    float* h0  = (float*)(ws + H0_OFF);
    float* hA  = (float*)(ws + HA_OFF);
    float* hB  = (float*)(ws + HB_OFF);
    float* outp = (float*)d_out;

    fused_prep<<<5024, 256, 0, stream>>>(x, freq,
                                         bw0, sw0, ss0, bw1, sw1, ss1, bw2, sw2, ss2,
                                         Wh0, Wl0, Wh1, Wl1, Wh2, Wl2, h0);

    layer_mfma<32><<<N_PTS / 64, 256, 0, stream>>>(h0, Wh0, Wl0, hA);
    layer_mfma<256><<<N_PTS / 64, 256, 0, stream>>>(hA, Wh1, Wl1, hB);
    layer_mfma<256><<<N_PTS / 64, 256, 0, stream>>>(hB, Wh2, Wl2, hA);

    layer3_kernel<<<(N_PTS * 64) / 256, 256, 0, stream>>>(hA, sw3, ss3, bw3, outp);
}